// Round 2
// 344.138 us; speedup vs baseline: 1.1562x; 1.1562x over previous
//
#include <hip/hip_runtime.h>
#include <hip/hip_bf16.h>

typedef __bf16 bf16x8 __attribute__((ext_vector_type(8)));
typedef float f32x4 __attribute__((ext_vector_type(4)));

#define B_ 16
#define N_ 2048
#define C_ 512
#define D_ 64

__device__ __forceinline__ float bf2f(ushort u) {
    union { uint i; float f; } w; w.i = ((uint)u) << 16; return w.f;
}
__device__ __forceinline__ ushort f2bf(float f) {
    union { float f; uint i; } w; w.f = f;
    uint u = w.i;
    u = (u + 0x7fffu + ((u >> 16) & 1u)) >> 16;
    return (ushort)u;
}
__device__ __forceinline__ __bf16 u2b(ushort u) {
    union { ushort s; __bf16 b; } w; w.s = u; return w.b;
}
__device__ __forceinline__ bf16x8 ld8u(const ushort* p) { return *(const bf16x8*)p; }
__device__ __forceinline__ bf16x8 ld8f(const float* p) {
    f32x4 a = *(const f32x4*)p;
    f32x4 b = *(const f32x4*)(p + 4);
    bf16x8 r;
    r[0] = u2b(f2bf(a[0])); r[1] = u2b(f2bf(a[1]));
    r[2] = u2b(f2bf(a[2])); r[3] = u2b(f2bf(a[3]));
    r[4] = u2b(f2bf(b[0])); r[5] = u2b(f2bf(b[1]));
    r[6] = u2b(f2bf(b[2])); r[7] = u2b(f2bf(b[3]));
    return r;
}

// async global->LDS, 16 B per lane; LDS dest = wave-uniform base + lane*16
__device__ __forceinline__ void gload16(const ushort* g, ushort* l) {
    __builtin_amdgcn_global_load_lds(
        (const __attribute__((address_space(1))) void*)g,
        (__attribute__((address_space(3))) void*)l, 16, 0, 0);
}

// Decide whether float tensors are stored as f32 or bf16 (bench: f32).
__global__ void probe_kernel(const void* x, int* flag) {
    int lane = threadIdx.x & 63;
    ushort u = ((const ushort*)x)[lane * 2];
    float v = fabsf(bf2f(u));
    bool sane = (v > 9.3e-10f) && (v < 1.1e9f) && (v == v);
    unsigned long long m = __ballot(sane);
    if (threadIdx.x == 0) *flag = (__popcll(m) >= 48) ? 0 : 1;  // 0=bf16, 1=f32
}

// Merged Q+K projection: out[m, n] = sum_k X[m,k] * W{q,k}[n,k] + b{q,k}[n]
// One pass over X (the dominant traffic) instead of two.
__launch_bounds__(256, 2)
__global__ void proj_qk_kernel(const void* __restrict__ X,
                               const void* __restrict__ Wq_,
                               const void* __restrict__ bq_,
                               const void* __restrict__ Wk_,
                               const void* __restrict__ bk_,
                               ushort* __restrict__ outq,
                               ushort* __restrict__ outk,
                               const int* __restrict__ flag) {
    const int isf32 = *flag;
    const ushort* Xu  = (const ushort*)X;
    const float*  Xf  = (const float*)X;
    const ushort* Wqu = (const ushort*)Wq_;
    const float*  Wqf = (const float*)Wq_;
    const ushort* Wku = (const ushort*)Wk_;
    const float*  Wkf = (const float*)Wk_;
    const ushort* Bqu = (const ushort*)bq_;
    const float*  Bqf = (const float*)bq_;
    const ushort* Bku = (const ushort*)bk_;
    const float*  Bkf = (const float*)bk_;

    __shared__ ushort lA[64][72];
    __shared__ ushort lBq[64][72];
    __shared__ ushort lBk[64][72];
    const int tid  = threadIdx.x;
    const int wave = tid >> 6, lane = tid & 63;
    const int quad = lane >> 4, li = lane & 15;
    const int m0 = blockIdx.x * 64;

    f32x4 accq[4], acck[4];
    #pragma unroll
    for (int t = 0; t < 4; ++t) {
        accq[t] = (f32x4){0.f, 0.f, 0.f, 0.f};
        acck[t] = (f32x4){0.f, 0.f, 0.f, 0.f};
    }

    for (int k0 = 0; k0 < C_; k0 += 64) {
        __syncthreads();
        #pragma unroll
        for (int it = 0; it < 2; ++it) {
            int idx = tid + it * 256;
            int row = idx >> 3, seg = idx & 7;
            size_t ea = (size_t)(m0 + row) * C_ + k0 + seg * 8;
            size_t eb = (size_t)row * C_ + k0 + seg * 8;
            if (!isf32) {
                *(bf16x8*)&lA[row][seg * 8]  = ld8u(Xu + ea);
                *(bf16x8*)&lBq[row][seg * 8] = ld8u(Wqu + eb);
                *(bf16x8*)&lBk[row][seg * 8] = ld8u(Wku + eb);
            } else {
                *(bf16x8*)&lA[row][seg * 8]  = ld8f(Xf + ea);
                *(bf16x8*)&lBq[row][seg * 8] = ld8f(Wqf + eb);
                *(bf16x8*)&lBk[row][seg * 8] = ld8f(Wkf + eb);
            }
        }
        __syncthreads();
        #pragma unroll
        for (int ks = 0; ks < 2; ++ks) {
            bf16x8 a = *(const bf16x8*)&lA[wave * 16 + li][ks * 32 + quad * 8];
            #pragma unroll
            for (int t = 0; t < 4; ++t) {
                bf16x8 bq8 = *(const bf16x8*)&lBq[t * 16 + li][ks * 32 + quad * 8];
                bf16x8 bk8 = *(const bf16x8*)&lBk[t * 16 + li][ks * 32 + quad * 8];
                accq[t] = __builtin_amdgcn_mfma_f32_16x16x32_bf16(a, bq8, accq[t], 0, 0, 0);
                acck[t] = __builtin_amdgcn_mfma_f32_16x16x32_bf16(a, bk8, acck[t], 0, 0, 0);
            }
        }
    }

    #pragma unroll
    for (int t = 0; t < 4; ++t) {
        int c = t * 16 + li;
        float bvq = isf32 ? Bqf[c] : bf2f(Bqu[c]);
        float bvk = isf32 ? Bkf[c] : bf2f(Bku[c]);
        #pragma unroll
        for (int j = 0; j < 4; ++j) {
            int m = m0 + wave * 16 + quad * 4 + j;
            outq[(size_t)m * D_ + c] = f2bf(accq[t][j] + bvq);
            outk[(size_t)m * D_ + c] = f2bf(acck[t][j] + bvk);
        }
    }
}

// Generic B^T GEMM: out[m, n] = sum_k X[m,k] * W[n,k] + bias[n]
// MODE 1: out transposed per batch (v_t). (MODE 0 path kept for reference.)
template<int NCOLS, int MODE>
__launch_bounds__(256, 2)
__global__ void proj_kernel(const void* __restrict__ X,
                            const void* __restrict__ W,
                            const void* __restrict__ bias,
                            ushort* __restrict__ out,
                            const int* __restrict__ flag,
                            size_t xoff) {
    const int isf32 = *flag;
    const ushort* Xu = (const ushort*)X + xoff;
    const float*  Xf = (const float*)X + xoff;
    const ushort* Wu = (const ushort*)W;
    const float*  Wf = (const float*)W;
    const ushort* Bu = (const ushort*)bias;
    const float*  Bf = (const float*)bias;

    __shared__ ushort lA[64][72];
    __shared__ ushort lB[64][72];
    const int tid  = threadIdx.x;
    const int wave = tid >> 6, lane = tid & 63;
    const int quad = lane >> 4, li = lane & 15;
    const int m0 = blockIdx.x * 64;
    const int n0 = blockIdx.y * 64;

    f32x4 acc[4];
    #pragma unroll
    for (int t = 0; t < 4; ++t) acc[t] = (f32x4){0.f, 0.f, 0.f, 0.f};

    for (int k0 = 0; k0 < C_; k0 += 64) {
        __syncthreads();
        #pragma unroll
        for (int it = 0; it < 2; ++it) {
            int idx = tid + it * 256;
            int row = idx >> 3, seg = idx & 7;
            size_t ea = (size_t)(m0 + row) * C_ + k0 + seg * 8;
            size_t eb = (size_t)(n0 + row) * C_ + k0 + seg * 8;
            if (!isf32) {
                *(bf16x8*)&lA[row][seg * 8] = ld8u(Xu + ea);
                *(bf16x8*)&lB[row][seg * 8] = ld8u(Wu + eb);
            } else {
                *(bf16x8*)&lA[row][seg * 8] = ld8f(Xf + ea);
                *(bf16x8*)&lB[row][seg * 8] = ld8f(Wf + eb);
            }
        }
        __syncthreads();
        #pragma unroll
        for (int ks = 0; ks < 2; ++ks) {
            bf16x8 a = *(const bf16x8*)&lA[wave * 16 + li][ks * 32 + quad * 8];
            #pragma unroll
            for (int t = 0; t < 4; ++t) {
                bf16x8 b = *(const bf16x8*)&lB[t * 16 + li][ks * 32 + quad * 8];
                acc[t] = __builtin_amdgcn_mfma_f32_16x16x32_bf16(a, b, acc[t], 0, 0, 0);
            }
        }
    }

    #pragma unroll
    for (int t = 0; t < 4; ++t) {
        int c = n0 + t * 16 + li;
        float bv = isf32 ? Bf[c] : bf2f(Bu[c]);
        if (MODE == 0) {
            #pragma unroll
            for (int j = 0; j < 4; ++j) {
                int m = m0 + wave * 16 + quad * 4 + j;
                out[(size_t)m * NCOLS + c] = f2bf(acc[t][j] + bv);
            }
        } else {
            int m = m0 + wave * 16 + quad * 4;
            int b = m >> 11, ml = m & (N_ - 1);
            ushort4 pk;
            pk.x = f2bf(acc[t][0] + bv);
            pk.y = f2bf(acc[t][1] + bv);
            pk.z = f2bf(acc[t][2] + bv);
            pk.w = f2bf(acc[t][3] + bv);
            *(ushort4*)(out + ((size_t)(b * C_ + c)) * N_ + ml) = pk;
        }
    }
}

// m97-style 128x128 GEMM, B^T convention: D[n, c] = sum_k A[n,k] * B[c,k].
// global_load_lds (16B/lane) staging into XOR-swizzled LDS (granule g of row r
// stored at r*8 + (g ^ (r&7)) -> conflict-free ds_read_b128 fragments).
// EPI 0: P~ = exp(min(D,60)) -> bf16 Sout; row sums atomically into lrow.
//        (no max-subtraction: scores are O(10), exp safe in f32/bf16; the
//         shift cancels exactly in the normalized output)
// EPI 1: out = gamma * D / l[n] + x         (O = P~ V, fused epilogue)
template<int KTOT, int SA, int SB, int EPI>
__launch_bounds__(256, 2)
__global__ void gemm128(const ushort* __restrict__ Abase,
                        const ushort* __restrict__ Bbase,
                        ushort* __restrict__ Sout,
                        float* __restrict__ lrow,
                        const void* __restrict__ x,
                        const void* __restrict__ gptr,
                        void* __restrict__ out,
                        const int* __restrict__ flag,
                        int b0, size_t aBS, size_t bBS) {
    __shared__ ushort lA[128 * 64];
    __shared__ ushort lB[128 * 64];
    const int tid  = threadIdx.x;
    const int wave = tid >> 6, lane = tid & 63;
    const int quad = lane >> 4, li = lane & 15;
    const int wr = (wave & 1) * 64;    // wave's row block within the 128-tile
    const int wc = (wave >> 1) * 64;   // wave's col block
    const int bz = blockIdx.z;
    const int m0 = blockIdx.x * 128;   // n rows
    const int c0 = blockIdx.y * 128;   // cols (B rows)
    const ushort* A  = Abase + (size_t)bz * aBS;
    const ushort* Bp = Bbase + (size_t)bz * bBS;

    // staging lane constants: lane covers row (+lane>>3), XOR'd k-segment
    const int lrow8 = lane >> 3;
    const int lseg  = (lane & 7) ^ (lrow8 & 7);

    f32x4 acc[4][4];
    #pragma unroll
    for (int i = 0; i < 4; ++i)
        #pragma unroll
        for (int j = 0; j < 4; ++j) acc[i][j] = (f32x4){0.f, 0.f, 0.f, 0.f};

    for (int k0 = 0; k0 < KTOT; k0 += 64) {
        __syncthreads();   // prev iter's ds_reads done before overwrite
        #pragma unroll
        for (int i = 0; i < 4; ++i) {
            int rbase = wave * 32 + i * 8;
            int rA = m0 + rbase + lrow8;
            int rB = c0 + rbase + lrow8;
            gload16(A  + (size_t)rA * SA + k0 + lseg * 8, &lA[rbase * 64]);
            gload16(Bp + (size_t)rB * SB + k0 + lseg * 8, &lB[rbase * 64]);
        }
        __syncthreads();   // drains vmcnt: LDS tiles ready

        #pragma unroll
        for (int ks = 0; ks < 2; ++ks) {
            bf16x8 af[4], bfr[4];
            #pragma unroll
            for (int i = 0; i < 4; ++i) {
                int row = wr + i * 16 + li;
                af[i] = *(const bf16x8*)&lA[row * 64 + (((ks * 4 + quad) ^ (li & 7)) * 8)];
            }
            #pragma unroll
            for (int j = 0; j < 4; ++j) {
                int row = wc + j * 16 + li;
                bfr[j] = *(const bf16x8*)&lB[row * 64 + (((ks * 4 + quad) ^ (li & 7)) * 8)];
            }
            #pragma unroll
            for (int i = 0; i < 4; ++i)
                #pragma unroll
                for (int j = 0; j < 4; ++j)
                    acc[i][j] = __builtin_amdgcn_mfma_f32_16x16x32_bf16(
                        af[i], bfr[j], acc[i][j], 0, 0, 0);
        }
    }

    if (EPI == 0) {
        ushort* Sb = Sout + (size_t)bz * N_ * N_;
        float*  lb = lrow + (size_t)bz * N_;
        #pragma unroll
        for (int i = 0; i < 4; ++i)
            #pragma unroll
            for (int j = 0; j < 4; ++j) {
                int n = m0 + wr + i * 16 + quad * 4 + j;
                float s4 = 0.f;
                #pragma unroll
                for (int j2 = 0; j2 < 4; ++j2) {
                    int m = c0 + wc + j2 * 16 + li;
                    float e = __expf(fminf(acc[i][j2][j], 60.f));
                    Sb[(size_t)n * N_ + m] = f2bf(e);
                    s4 += e;
                }
                // reduce the 16 lanes of this quad -> 64-col partial row sum
                s4 += __shfl_xor(s4, 1, 64);
                s4 += __shfl_xor(s4, 2, 64);
                s4 += __shfl_xor(s4, 4, 64);
                s4 += __shfl_xor(s4, 8, 64);
                if (li == 0) atomicAdd(&lb[n], s4);
            }
    } else {
        const int isf32 = *flag;
        const ushort* xu = (const ushort*)x;
        const float*  xf = (const float*)x;
        ushort* ou = (ushort*)out;
        float*  of = (float*)out;
        float g = isf32 ? ((const float*)gptr)[0] : bf2f(((const ushort*)gptr)[0]);
        #pragma unroll
        for (int i = 0; i < 4; ++i) {
            #pragma unroll
            for (int j = 0; j < 4; ++j) {
                int n = m0 + wr + i * 16 + quad * 4 + j;
                float inv = 1.f / lrow[(size_t)bz * N_ + n];
                size_t rowb = ((size_t)((b0 + bz) * N_ + n)) * C_;
                #pragma unroll
                for (int j2 = 0; j2 < 4; ++j2) {
                    int c = c0 + wc + j2 * 16 + li;
                    size_t idx = rowb + c;
                    float xv  = isf32 ? xf[idx] : bf2f(xu[idx]);
                    float val = g * (acc[i][j2][j] * inv) + xv;
                    if (isf32) of[idx] = val; else ou[idx] = f2bf(val);
                }
            }
        }
    }
}

extern "C" void kernel_launch(void* const* d_in, const int* in_sizes, int n_in,
                              void* d_out, int out_size, void* d_ws, size_t ws_size,
                              hipStream_t stream) {
    (void)in_sizes; (void)n_in; (void)out_size;
    const void* x     = d_in[0];
    const void* Wq    = d_in[1];
    const void* bq    = d_in[2];
    const void* Wk    = d_in[3];
    const void* bk    = d_in[4];
    const void* Wv    = d_in[5];
    const void* bv    = d_in[6];
    const void* gamma = d_in[7];

    // choose batch-group size from ws_size (constant across calls -> graph-safe)
    // need(bh) = 256 + q(4M) + k(4M) + bh*( vt 2M + S 8M + l 8K )
    auto need = [](int bh) -> size_t {
        return 256 + 2 * (size_t)B_ * N_ * D_ * 2 +
               (size_t)bh * ((size_t)C_ * N_ * 2 + (size_t)N_ * N_ * 2 + (size_t)N_ * 4);
    };
    int BHg = 1;
    if      (need(16) <= ws_size) BHg = 16;
    else if (need(8)  <= ws_size) BHg = 8;
    else if (need(4)  <= ws_size) BHg = 4;
    else if (need(2)  <= ws_size) BHg = 2;

    int*    flag = (int*)d_ws;
    ushort* q    = (ushort*)((char*)d_ws + 256);
    ushort* kk   = q  + (size_t)B_ * N_ * D_;           // [B, N, 64] bf16
    ushort* vt   = kk + (size_t)B_ * N_ * D_;           // [BHg, C, N] bf16
    ushort* S    = vt + (size_t)BHg * C_ * N_;          // [BHg, N, N] bf16
    float*  lrow = (float*)(S + (size_t)BHg * N_ * N_); // [BHg, N]

    probe_kernel<<<1, 64, 0, stream>>>(x, flag);

    const int M = B_ * N_;  // 32768
    proj_qk_kernel<<<dim3(M / 64), 256, 0, stream>>>(x, Wq, bq, Wk, bk, q, kk, flag);

    for (int b0 = 0; b0 < B_; b0 += BHg) {
        const size_t xoff = (size_t)b0 * N_ * C_;
        const size_t qoff = (size_t)b0 * N_ * D_;
        proj_kernel<C_, 1><<<dim3(BHg * N_ / 64, C_ / 64), 256, 0, stream>>>(
            x, Wv, bv, vt, flag, xoff);
        hipMemsetAsync(lrow, 0, (size_t)BHg * N_ * sizeof(float), stream);
        gemm128<64, 64, 64, 0><<<dim3(16, 16, BHg), 256, 0, stream>>>(
            q + qoff, kk + qoff, S, lrow, x, gamma, d_out, flag, b0,
            (size_t)N_ * D_, (size_t)N_ * D_);
        gemm128<2048, 2048, 2048, 1><<<dim3(16, 4, BHg), 256, 0, stream>>>(
            S, vt, S, lrow, x, gamma, d_out, flag, b0,
            (size_t)N_ * N_, (size_t)C_ * N_);
    }
}